// Round 1
// baseline (235.093 us; speedup 1.0000x reference)
//
#include <hip/hip_runtime.h>
#include <hip/hip_bf16.h>
#include <stdint.h>

#define B_   2
#define S_   2048
#define HID_ 1024
#define NH_  16
#define HD_  64

typedef __attribute__((ext_vector_type(4))) float f32x4;
typedef __attribute__((ext_vector_type(8))) short bf16x8;

__device__ inline unsigned short f2bf(float x) {
    __hip_bfloat16 h = __float2bfloat16(x);
    return reinterpret_cast<unsigned short&>(h);
}

// ---------------------------------------------------------------------------
// QKV projection: out[m,n] = sum_k X[m,k]*W[n,k] + bias[n]   (torch x @ W.T + b)
// X: [4096,1024] fp32, W: [1024,1024] fp32, out: bf16 [4096,1024]
// 128x128 tile, BK=64, 4 waves (2x2), 4x4 fragments of 16x16x32 bf16 MFMA.
// fp32->bf16 conversion fused into LDS staging.
// ---------------------------------------------------------------------------
__global__ __launch_bounds__(256) void qkv_gemm(
    const float* __restrict__ X1, const float* __restrict__ X2,
    const float* __restrict__ Wq, const float* __restrict__ Wk, const float* __restrict__ Wv,
    const float* __restrict__ bq, const float* __restrict__ bk, const float* __restrict__ bv,
    unsigned short* __restrict__ Qo, unsigned short* __restrict__ Ko, unsigned short* __restrict__ Vo)
{
    const int z = blockIdx.z;
    const float* X    = (z == 0) ? X1 : X2;
    const float* W    = (z == 0) ? Wq : (z == 1 ? Wk : Wv);
    const float* bias = (z == 0) ? bq : (z == 1 ? bk : bv);
    unsigned short* out = (z == 0) ? Qo : (z == 1 ? Ko : Vo);

    __shared__ __align__(16) unsigned short As[128 * 72];
    __shared__ __align__(16) unsigned short Bs[128 * 72];

    const int m0 = blockIdx.x * 128;
    const int n0 = blockIdx.y * 128;
    const int t = threadIdx.x;
    const int lane = t & 63;
    const int w = t >> 6;
    const int lo = lane & 15, hi = lane >> 4;
    const int wm = w >> 1, wn = w & 1;
    const int srow = t >> 3;          // 0..31
    const int scol = (t & 7) * 8;     // 0..56

    f32x4 acc[4][4];
    const f32x4 fzero = {0.f, 0.f, 0.f, 0.f};
    #pragma unroll
    for (int i = 0; i < 4; ++i)
        #pragma unroll
        for (int j = 0; j < 4; ++j) acc[i][j] = fzero;

    for (int kt = 0; kt < HID_; kt += 64) {
        __syncthreads();
        #pragma unroll
        for (int p = 0; p < 4; ++p) {
            int r = p * 32 + srow;
            const float* xr = X + (size_t)(m0 + r) * HID_ + kt + scol;
            const float* wr = W + (size_t)(n0 + r) * HID_ + kt + scol;
            float4 a0 = *(const float4*)xr;
            float4 a1 = *(const float4*)(xr + 4);
            float4 b0 = *(const float4*)wr;
            float4 b1 = *(const float4*)(wr + 4);
            unsigned short ta[8] = {f2bf(a0.x), f2bf(a0.y), f2bf(a0.z), f2bf(a0.w),
                                    f2bf(a1.x), f2bf(a1.y), f2bf(a1.z), f2bf(a1.w)};
            unsigned short tb[8] = {f2bf(b0.x), f2bf(b0.y), f2bf(b0.z), f2bf(b0.w),
                                    f2bf(b1.x), f2bf(b1.y), f2bf(b1.z), f2bf(b1.w)};
            *(uint4*)&As[r * 72 + scol] = *(uint4*)ta;
            *(uint4*)&Bs[r * 72 + scol] = *(uint4*)tb;
        }
        __syncthreads();
        #pragma unroll
        for (int s = 0; s < 2; ++s) {
            bf16x8 a[4], b[4];
            #pragma unroll
            for (int i = 0; i < 4; ++i) {
                a[i] = *(const bf16x8*)&As[(wm * 64 + i * 16 + lo) * 72 + s * 32 + hi * 8];
                b[i] = *(const bf16x8*)&Bs[(wn * 64 + i * 16 + lo) * 72 + s * 32 + hi * 8];
            }
            #pragma unroll
            for (int i = 0; i < 4; ++i)
                #pragma unroll
                for (int j = 0; j < 4; ++j)
                    acc[i][j] = __builtin_amdgcn_mfma_f32_16x16x32_bf16(a[i], b[j], acc[i][j], 0, 0, 0);
        }
    }

    #pragma unroll
    for (int i = 0; i < 4; ++i) {
        #pragma unroll
        for (int j = 0; j < 4; ++j) {
            int col = n0 + wn * 64 + j * 16 + lo;
            float bb = bias[col];
            #pragma unroll
            for (int r = 0; r < 4; ++r) {
                int row = m0 + wm * 64 + i * 16 + hi * 4 + r;
                out[(size_t)row * HID_ + col] = f2bf(acc[i][j][r] + bb);
            }
        }
    }
}

// ---------------------------------------------------------------------------
// Flash attention: one block = 64 q-rows of one (b,h). 4 waves x 16 q-rows.
// Q/K/V bf16 [B*S, 1024] (head h at cols h*64..h*64+63). out fp32 [B,S,1024].
// ---------------------------------------------------------------------------
__global__ __launch_bounds__(256) void attn_fwd(
    const unsigned short* __restrict__ Q, const unsigned short* __restrict__ K,
    const unsigned short* __restrict__ V, float* __restrict__ out)
{
    __shared__ __align__(16) unsigned short Qs[64 * 72];
    __shared__ __align__(16) unsigned short Ks[64 * 72];
    __shared__ __align__(16) unsigned short Vt[64 * 72];   // transposed: Vt[d][k]
    __shared__ __align__(16) unsigned short Ps[4 * 16 * 72];

    const int t = threadIdx.x;
    const int lane = t & 63;
    const int w = t >> 6;
    const int lo = lane & 15, hi = lane >> 4;

    const int q0 = blockIdx.x * 64;
    const int bh = blockIdx.y;
    const int b = bh >> 4, h = bh & 15;

    const size_t base = (size_t)b * S_ * HID_ + (size_t)h * HD_;

    // stage Q tile [64][64]
    {
        int r = t >> 3;
        int c = (t & 7) * 8;
        *(uint4*)&Qs[r * 72 + c]        = *(const uint4*)&Q[base + (size_t)(q0 + r) * HID_ + c];
        *(uint4*)&Qs[(r + 32) * 72 + c] = *(const uint4*)&Q[base + (size_t)(q0 + r + 32) * HID_ + c];
    }
    __syncthreads();

    // hoist this wave's Q A-fragments (rows w*16..w*16+15)
    bf16x8 qa0 = *(const bf16x8*)&Qs[(w * 16 + lo) * 72 + hi * 8];
    bf16x8 qa1 = *(const bf16x8*)&Qs[(w * 16 + lo) * 72 + 32 + hi * 8];

    f32x4 O[4];
    const f32x4 fzero = {0.f, 0.f, 0.f, 0.f};
    #pragma unroll
    for (int c = 0; c < 4; ++c) O[c] = fzero;
    float mrun[4] = {-3.0e38f, -3.0e38f, -3.0e38f, -3.0e38f};
    float lrun[4] = {0.f, 0.f, 0.f, 0.f};

    unsigned short* Pw = &Ps[w * 16 * 72];

    for (int k0 = 0; k0 < S_; k0 += 64) {
        __syncthreads();   // previous tile's LDS reads done
        {
            int r = t >> 3;
            int c = (t & 7) * 8;
            #pragma unroll
            for (int p = 0; p < 2; ++p) {
                int rr = r + p * 32;
                *(uint4*)&Ks[rr * 72 + c] = *(const uint4*)&K[base + (size_t)(k0 + rr) * HID_ + c];
                uint4 vv = *(const uint4*)&V[base + (size_t)(k0 + rr) * HID_ + c];
                const unsigned short* vs = (const unsigned short*)&vv;
                #pragma unroll
                for (int j = 0; j < 8; ++j)
                    Vt[(c + j) * 72 + rr] = vs[j];
            }
        }
        __syncthreads();

        // scores S = Q K^T (wave computes 16x64), scaled by 1/8
        f32x4 s[4];
        #pragma unroll
        for (int n = 0; n < 4; ++n) {
            bf16x8 kb0 = *(const bf16x8*)&Ks[(n * 16 + lo) * 72 + hi * 8];
            bf16x8 kb1 = *(const bf16x8*)&Ks[(n * 16 + lo) * 72 + 32 + hi * 8];
            f32x4 zacc = fzero;
            zacc = __builtin_amdgcn_mfma_f32_16x16x32_bf16(qa0, kb0, zacc, 0, 0, 0);
            s[n] = __builtin_amdgcn_mfma_f32_16x16x32_bf16(qa1, kb1, zacc, 0, 0, 0);
            s[n] *= 0.125f;
        }

        // online softmax (each lane owns 4 rows hi*4+r, col lo+16n)
        float alpha[4], rs[4];
        #pragma unroll
        for (int r = 0; r < 4; ++r) {
            float rm = -3.0e38f;
            #pragma unroll
            for (int n = 0; n < 4; ++n) rm = fmaxf(rm, s[n][r]);
            #pragma unroll
            for (int msk = 1; msk < 16; msk <<= 1)
                rm = fmaxf(rm, __shfl_xor(rm, msk));
            float mn = fmaxf(mrun[r], rm);
            alpha[r] = __expf(mrun[r] - mn);
            float sum = 0.f;
            #pragma unroll
            for (int n = 0; n < 4; ++n) {
                float p = __expf(s[n][r] - mn);
                s[n][r] = p;
                sum += p;
            }
            #pragma unroll
            for (int msk = 1; msk < 16; msk <<= 1)
                sum += __shfl_xor(sum, msk);
            rs[r] = sum;
            mrun[r] = mn;
            lrun[r] = lrun[r] * alpha[r] + rs[r];
        }
        #pragma unroll
        for (int r = 0; r < 4; ++r)
            #pragma unroll
            for (int c = 0; c < 4; ++c)
                O[c][r] *= alpha[r];

        // P -> LDS (bf16) to re-layout as A operand
        #pragma unroll
        for (int n = 0; n < 4; ++n)
            #pragma unroll
            for (int r = 0; r < 4; ++r)
                Pw[(hi * 4 + r) * 72 + n * 16 + lo] = f2bf(s[n][r]);

        // O += P V
        #pragma unroll
        for (int st = 0; st < 2; ++st) {
            bf16x8 pa = *(const bf16x8*)&Pw[lo * 72 + st * 32 + hi * 8];
            #pragma unroll
            for (int c = 0; c < 4; ++c) {
                bf16x8 vb = *(const bf16x8*)&Vt[(c * 16 + lo) * 72 + st * 32 + hi * 8];
                O[c] = __builtin_amdgcn_mfma_f32_16x16x32_bf16(pa, vb, O[c], 0, 0, 0);
            }
        }
    }

    // epilogue: normalize and store fp32
    #pragma unroll
    for (int c = 0; c < 4; ++c) {
        #pragma unroll
        for (int r = 0; r < 4; ++r) {
            int q = q0 + w * 16 + hi * 4 + r;
            out[(size_t)b * S_ * HID_ + (size_t)q * HID_ + h * HD_ + c * 16 + lo] =
                O[c][r] / lrun[r];
        }
    }
}

extern "C" void kernel_launch(void* const* d_in, const int* in_sizes, int n_in,
                              void* d_out, int out_size, void* d_ws, size_t ws_size,
                              hipStream_t stream) {
    const float* hs1 = (const float*)d_in[0];
    const float* hs2 = (const float*)d_in[1];
    const float* Wq  = (const float*)d_in[2];
    const float* bq  = (const float*)d_in[3];
    const float* Wk  = (const float*)d_in[4];
    const float* bk  = (const float*)d_in[5];
    const float* Wv  = (const float*)d_in[6];
    const float* bv  = (const float*)d_in[7];
    float* out = (float*)d_out;

    const size_t QKV_ELEMS = (size_t)B_ * S_ * HID_;  // 4194304
    unsigned short* Qb = (unsigned short*)d_ws;
    unsigned short* Kb = Qb + QKV_ELEMS;
    unsigned short* Vb = Kb + QKV_ELEMS;

    // QKV projections: M=4096, N=1024, 3 matrices
    qkv_gemm<<<dim3(32, 8, 3), 256, 0, stream>>>(hs1, hs2, Wq, Wk, Wv, bq, bk, bv, Qb, Kb, Vb);

    // attention: 32 q-tiles x (B*NH=32)
    attn_fwd<<<dim3(S_ / 64, B_ * NH_), 256, 0, stream>>>(Qb, Kb, Vb, out);
}